// Round 17
// baseline (1486.783 us; speedup 1.0000x reference)
//
#include <hip/hip_runtime.h>
#include <cstdint>
#include <cstddef>

#define L_SEQ 4096
#define BATCH 32
#define DIN 128
#define DLAT 512
#define CHUNK 32
#define NCHUNK (L_SEQ / CHUNK)   // 128
#define USTRIDE 522
#define NITEMS (NCHUNK * BATCH)  // 4096

typedef __attribute__((ext_vector_type(8))) short short8;
typedef __attribute__((ext_vector_type(4))) float f32x4;

__device__ __forceinline__ unsigned short bf16rne(float x) {
    unsigned int b = __builtin_bit_cast(unsigned int, x);
    unsigned int r = b + 0x7FFFu + ((b >> 16) & 1u);
    return (unsigned short)(r >> 16);
}
__device__ __forceinline__ float bf16tof(unsigned short h) {
    return __builtin_bit_cast(float, (unsigned int)h << 16);
}
__device__ __forceinline__ void bf16split3(float x, unsigned short& h,
                                           unsigned short& m, unsigned short& l) {
    h = bf16rne(x);
    float r1 = x - bf16tof(h);
    m = bf16rne(r1);
    float r2 = r1 - bf16tof(m);
    l = bf16rne(r2);
}
__device__ __forceinline__ float pow32(float x) {
    float t = x;
    t = t * t; t = t * t; t = t * t; t = t * t; t = t * t;
    return t;
}

// ---------------------------------------------------------------------------
// Kernel W: wx [128][512] fp32 -> MFMA B-frag layout, bf16 h/m/l (3x128 KB).
// ---------------------------------------------------------------------------
__global__ __launch_bounds__(256) void wx_transform(
    const float* __restrict__ wx,
    unsigned short* __restrict__ wxtH,
    unsigned short* __restrict__ wxtM,
    unsigned short* __restrict__ wxtL)
{
    const int gid  = blockIdx.x * 256 + threadIdx.x;
    const int fid  = gid >> 6;
    const int lane = gid & 63;
    const int kt = fid >> 5, nt = fid & 31;
    const int n  = nt * 16 + (lane & 15);
    const int kb = kt * 32 + (lane >> 4) * 8;

    short8 h8, m8, l8;
#pragma unroll
    for (int i = 0; i < 8; ++i) {
        unsigned short h, m, l;
        bf16split3(wx[(size_t)(kb + i) * DLAT + n], h, m, l);
        h8[i] = (short)h; m8[i] = (short)m; l8[i] = (short)l;
    }
    ((short8*)wxtH)[fid * 64 + lane] = h8;
    ((short8*)wxtM)[fid * 64 + lane] = m8;
    ((short8*)wxtL)[fid * 64 + lane] = l8;
}

// ---------------------------------------------------------------------------
// FUSED kernel: one dispatch does GEMM + chunk scan + cross-chunk lookback +
// tanh + final out. Key difference vs R15 (which spilled): NO per-thread
// locals array. acc[2][8] stays live; U is scanned TWICE:
//   pass 1 (init 0)  -> chunk-local F  -> publish flag=1
//   lookback (F/Hincl chain, atomic-claim order => deadlock-free; R15-proven)
//   publish Hincl = wh^32*H + F (flag=2)
//   pass 2 (init H)  -> s_t = fma(s, wh, u+bh)  == reference recurrence form
//                    -> out = tanh(s_t) directly. No 512 MB fix2 round-trip.
// grid 4096 blocks x 256 threads; each block claims ONE item via atomicAdd
// (claim order guarantees any awaited item is already running).
// ---------------------------------------------------------------------------
__global__ __launch_bounds__(256) void rnn_fused2(
    const float* __restrict__ X,
    const unsigned short* __restrict__ wxtH,
    const unsigned short* __restrict__ wxtM,
    const unsigned short* __restrict__ wxtL,
    const float* __restrict__ h0g,
    const float* __restrict__ wh,
    const float* __restrict__ bh,
    float* __restrict__ out,
    int* __restrict__ counter,
    int* __restrict__ flags,     // [NITEMS] 0=empty 1=F ready 2=Hincl ready
    float* __restrict__ F,       // [NCHUNK][BATCH][DLAT] chunk-local finals
    float* __restrict__ Hincl)   // [NCHUNK][BATCH][DLAT] inclusive states
{
    __shared__ __align__(16) char smem[16 * USTRIDE * 4];  // AF(24KB)/U(33.4KB) union
    __shared__ int s_item, s_stop;
    unsigned short* AF = (unsigned short*)smem;
    float* U = (float*)smem;

    const int tid  = threadIdx.x;
    const int wid  = tid >> 6, lane = tid & 63;
    const int ch   = tid * 2;

    if (tid == 0) s_item = atomicAdd(counter, 1);
    __syncthreads();
    const int item = s_item;
    if (item >= NITEMS) return;
    const int c = item >> 5, b = item & 31;

    const float2 whv = *(const float2*)(wh + ch);
    const float2 bhv = *(const float2*)(bh + ch);
    const float w32x = pow32(whv.x), w32y = pow32(whv.y);

    // ---- Phase S: stage + 3-way convert into AF ----
#pragma unroll
    for (int sl = 0; sl < 2; ++sl) {
        const int slot = tid + sl * 256;
        const int f  = slot >> 6;
        const int ls = slot & 63;
        const int m  = f >> 2, kt = f & 3;
        const int t  = c * CHUNK + m * 16 + (ls & 15);
        const int kb = kt * 32 + (ls >> 4) * 8;
        const float* p = X + ((size_t)t * BATCH + b) * DIN + kb;
        const float4 va = *(const float4*)p;
        const float4 vb = *(const float4*)(p + 4);
        float v[8] = {va.x, va.y, va.z, va.w, vb.x, vb.y, vb.z, vb.w};
        short8 h8, m8, l8;
#pragma unroll
        for (int i = 0; i < 8; ++i) {
            unsigned short h, mm, l;
            bf16split3(v[i], h, mm, l);
            h8[i] = (short)h; m8[i] = (short)mm; l8[i] = (short)l;
        }
        ((short8*)AF)[(f * 3 + 0) * 64 + ls] = h8;
        ((short8*)AF)[(f * 3 + 1) * 64 + ls] = m8;
        ((short8*)AF)[(f * 3 + 2) * 64 + ls] = l8;
    }
    __syncthreads();

    // ---- Phase M: 6-product MFMA emulation -> acc[2][8] (stays live) ----
    f32x4 acc[2][8];
#pragma unroll
    for (int m = 0; m < 2; ++m)
#pragma unroll
        for (int j = 0; j < 8; ++j)
            acc[m][j] = (f32x4){0.f, 0.f, 0.f, 0.f};

    const short8* AFv = (const short8*)AF;
    const short8* BHp = (const short8*)wxtH;
    const short8* BMp = (const short8*)wxtM;
    const short8* BLp = (const short8*)wxtL;

#pragma unroll
    for (int kt = 0; kt < 4; ++kt) {
        const short8 a0h = AFv[((0 * 4 + kt) * 3 + 0) * 64 + lane];
        const short8 a0m = AFv[((0 * 4 + kt) * 3 + 1) * 64 + lane];
        const short8 a0l = AFv[((0 * 4 + kt) * 3 + 2) * 64 + lane];
        const short8 a1h = AFv[((1 * 4 + kt) * 3 + 0) * 64 + lane];
        const short8 a1m = AFv[((1 * 4 + kt) * 3 + 1) * 64 + lane];
        const short8 a1l = AFv[((1 * 4 + kt) * 3 + 2) * 64 + lane];
#pragma unroll
        for (int j = 0; j < 8; ++j) {
            const int idx = (kt * 32 + wid * 8 + j) * 64 + lane;
            const short8 bh8 = BHp[idx];
            const short8 bm8 = BMp[idx];
            const short8 bl8 = BLp[idx];
            acc[0][j] = __builtin_amdgcn_mfma_f32_16x16x32_bf16(a0m, bm8, acc[0][j], 0, 0, 0);
            acc[0][j] = __builtin_amdgcn_mfma_f32_16x16x32_bf16(a0l, bh8, acc[0][j], 0, 0, 0);
            acc[0][j] = __builtin_amdgcn_mfma_f32_16x16x32_bf16(a0h, bl8, acc[0][j], 0, 0, 0);
            acc[0][j] = __builtin_amdgcn_mfma_f32_16x16x32_bf16(a0m, bh8, acc[0][j], 0, 0, 0);
            acc[0][j] = __builtin_amdgcn_mfma_f32_16x16x32_bf16(a0h, bm8, acc[0][j], 0, 0, 0);
            acc[0][j] = __builtin_amdgcn_mfma_f32_16x16x32_bf16(a0h, bh8, acc[0][j], 0, 0, 0);
            acc[1][j] = __builtin_amdgcn_mfma_f32_16x16x32_bf16(a1m, bm8, acc[1][j], 0, 0, 0);
            acc[1][j] = __builtin_amdgcn_mfma_f32_16x16x32_bf16(a1l, bh8, acc[1][j], 0, 0, 0);
            acc[1][j] = __builtin_amdgcn_mfma_f32_16x16x32_bf16(a1h, bl8, acc[1][j], 0, 0, 0);
            acc[1][j] = __builtin_amdgcn_mfma_f32_16x16x32_bf16(a1m, bh8, acc[1][j], 0, 0, 0);
            acc[1][j] = __builtin_amdgcn_mfma_f32_16x16x32_bf16(a1h, bm8, acc[1][j], 0, 0, 0);
            acc[1][j] = __builtin_amdgcn_mfma_f32_16x16x32_bf16(a1h, bh8, acc[1][j], 0, 0, 0);
        }
    }

    // ---- Pass 1: chunk-local scan (init 0) -> F. No out writes. ----
    float l0 = 0.f, l1 = 0.f;
#pragma unroll
    for (int m = 0; m < 2; ++m) {
        __syncthreads();   // m=0: AF reads done (union); m=1: prior U reads done
#pragma unroll
        for (int j = 0; j < 8; ++j) {
            const int col = wid * 128 + j * 16 + (lane & 15);
#pragma unroll
            for (int r4 = 0; r4 < 4; ++r4)
                U[((lane >> 4) * 4 + r4) * USTRIDE + col] = acc[m][j][r4];
        }
        __syncthreads();
#pragma unroll
        for (int tl = 0; tl < 16; ++tl) {
            const float2 u = *(const float2*)&U[tl * USTRIDE + ch];
            l0 = fmaf(l0, whv.x, u.x + bhv.x);
            l1 = fmaf(l1, whv.y, u.y + bhv.y);
        }
    }

    // ---- Publish F (wait-free) ----
    const size_t fbase = (size_t)item * DLAT + ch;
    {
        float2 fo; fo.x = l0; fo.y = l1;
        *(float2*)(F + fbase) = fo;
    }
    __threadfence();
    __syncthreads();
    if (tid == 0)
        __hip_atomic_store(&flags[item], 1, __ATOMIC_RELEASE, __HIP_MEMORY_SCOPE_AGENT);

    // ---- Decoupled lookback ----
    if (tid == 0) {
        int cc = c - 1;
        while (cc >= 0) {
            int f;
            while ((f = __hip_atomic_load(&flags[cc * 32 + b],
                                          __ATOMIC_ACQUIRE, __HIP_MEMORY_SCOPE_AGENT)) < 1)
                __builtin_amdgcn_s_sleep(2);
            if (f == 2) break;
            --cc;
        }
        s_stop = cc;
    }
    __syncthreads();
    const int stop = s_stop;

    float H0, H1;
    if (stop < 0) {
        const float2 h4 = *(const float2*)(h0g + (size_t)b * DLAT + ch);
        H0 = h4.x; H1 = h4.y;
    } else {
        unsigned long long uv = __hip_atomic_load(
            (const unsigned long long*)(Hincl + ((size_t)(stop * 32 + b) * DLAT + ch)),
            __ATOMIC_RELAXED, __HIP_MEMORY_SCOPE_AGENT);
        float2 hv = __builtin_bit_cast(float2, uv);
        H0 = hv.x; H1 = hv.y;
    }
    for (int cc = stop + 1; cc < c; ++cc) {
        unsigned long long uv = __hip_atomic_load(
            (const unsigned long long*)(F + ((size_t)(cc * 32 + b) * DLAT + ch)),
            __ATOMIC_RELAXED, __HIP_MEMORY_SCOPE_AGENT);
        float2 fv = __builtin_bit_cast(float2, uv);
        H0 = fmaf(H0, w32x, fv.x);
        H1 = fmaf(H1, w32y, fv.y);
    }

    // ---- Publish inclusive S[c] = wh^32*H + F[c] (same recurrence as prefix) ----
    {
        float2 so; so.x = fmaf(H0, w32x, l0); so.y = fmaf(H1, w32y, l1);
        *(float2*)(Hincl + fbase) = so;
    }
    __threadfence();
    __syncthreads();
    if (tid == 0)
        __hip_atomic_store(&flags[item], 2, __ATOMIC_RELEASE, __HIP_MEMORY_SCOPE_AGENT);

    // ---- Pass 2: re-scan with s init = H (exact reference recurrence form),
    //      emit tanh directly to out. acc still in registers. ----
    float s0 = H0, s1 = H1;
#pragma unroll
    for (int m = 0; m < 2; ++m) {
        __syncthreads();   // prior U reads done
#pragma unroll
        for (int j = 0; j < 8; ++j) {
            const int col = wid * 128 + j * 16 + (lane & 15);
#pragma unroll
            for (int r4 = 0; r4 < 4; ++r4)
                U[((lane >> 4) * 4 + r4) * USTRIDE + col] = acc[m][j][r4];
        }
        __syncthreads();
#pragma unroll
        for (int tl = 0; tl < 16; ++tl) {
            const float2 u = *(const float2*)&U[tl * USTRIDE + ch];
            s0 = fmaf(s0, whv.x, u.x + bhv.x);
            s1 = fmaf(s1, whv.y, u.y + bhv.y);
            const int t = c * CHUNK + m * 16 + tl;
            float2 o; o.x = tanhf(s0); o.y = tanhf(s1);
            *(float2*)(out + ((size_t)t * BATCH + b) * DLAT + ch) = o;
        }
    }
}

// ---------------------------------------------------------------------------
// Fallback chain (R16, proven 233 µs): used only if ws too small for fused.
// ---------------------------------------------------------------------------
__global__ __launch_bounds__(256) void rnn_local_mfma2(
    const float* __restrict__ X,
    const unsigned short* __restrict__ wxtH,
    const unsigned short* __restrict__ wxtM,
    const unsigned short* __restrict__ wxtL,
    const float* __restrict__ wh,
    const float* __restrict__ bh,
    float* __restrict__ out,
    float* __restrict__ F)
{
    __shared__ __align__(16) char smem[16 * 3 * 64 * 8 * 2];
    unsigned short* AF = (unsigned short*)smem;
    float* U = (float*)smem;
    const int tid  = threadIdx.x;
    const int c0 = blockIdx.x * 2, b = blockIdx.y;
    const int wid = tid >> 6, lane = tid & 63;
#pragma unroll
    for (int sl = 0; sl < 4; ++sl) {
        const int slot = tid + sl * 256;
        const int f  = slot >> 6;
        const int ls = slot & 63;
        const int cl = f >> 3, m = (f >> 2) & 1, kt = f & 3;
        const int t  = (c0 + cl) * CHUNK + m * 16 + (ls & 15);
        const int kb = kt * 32 + (ls >> 4) * 8;
        const float* p = X + ((size_t)t * BATCH + b) * DIN + kb;
        const float4 va = *(const float4*)p;
        const float4 vb = *(const float4*)(p + 4);
        float v[8] = {va.x, va.y, va.z, va.w, vb.x, vb.y, vb.z, vb.w};
        short8 h8, m8, l8;
#pragma unroll
        for (int i = 0; i < 8; ++i) {
            unsigned short h, mm, l;
            bf16split3(v[i], h, mm, l);
            h8[i] = (short)h; m8[i] = (short)mm; l8[i] = (short)l;
        }
        ((short8*)AF)[(f * 3 + 0) * 64 + ls] = h8;
        ((short8*)AF)[(f * 3 + 1) * 64 + ls] = m8;
        ((short8*)AF)[(f * 3 + 2) * 64 + ls] = l8;
    }
    __syncthreads();
    f32x4 acc[4][8];
#pragma unroll
    for (int tt = 0; tt < 4; ++tt)
#pragma unroll
        for (int j = 0; j < 8; ++j)
            acc[tt][j] = (f32x4){0.f, 0.f, 0.f, 0.f};
    const short8* AFv = (const short8*)AF;
    const short8* BHp = (const short8*)wxtH;
    const short8* BMp = (const short8*)wxtM;
    const short8* BLp = (const short8*)wxtL;
#pragma unroll
    for (int kt = 0; kt < 4; ++kt) {
        short8 ah[4], am[4], al[4];
#pragma unroll
        for (int tt = 0; tt < 4; ++tt) {
            const int f = tt * 4 + kt;
            ah[tt] = AFv[(f * 3 + 0) * 64 + lane];
            am[tt] = AFv[(f * 3 + 1) * 64 + lane];
            al[tt] = AFv[(f * 3 + 2) * 64 + lane];
        }
#pragma unroll
        for (int j = 0; j < 8; ++j) {
            const int idx = (kt * 32 + wid * 8 + j) * 64 + lane;
            const short8 bh8 = BHp[idx];
            const short8 bm8 = BMp[idx];
            const short8 bl8 = BLp[idx];
#pragma unroll
            for (int tt = 0; tt < 4; ++tt) {
                acc[tt][j] = __builtin_amdgcn_mfma_f32_16x16x32_bf16(am[tt], bm8, acc[tt][j], 0, 0, 0);
                acc[tt][j] = __builtin_amdgcn_mfma_f32_16x16x32_bf16(al[tt], bh8, acc[tt][j], 0, 0, 0);
                acc[tt][j] = __builtin_amdgcn_mfma_f32_16x16x32_bf16(ah[tt], bl8, acc[tt][j], 0, 0, 0);
                acc[tt][j] = __builtin_amdgcn_mfma_f32_16x16x32_bf16(am[tt], bh8, acc[tt][j], 0, 0, 0);
                acc[tt][j] = __builtin_amdgcn_mfma_f32_16x16x32_bf16(ah[tt], bm8, acc[tt][j], 0, 0, 0);
                acc[tt][j] = __builtin_amdgcn_mfma_f32_16x16x32_bf16(ah[tt], bh8, acc[tt][j], 0, 0, 0);
            }
        }
    }
    const int ch = tid * 2;
    const float2 whv = *(const float2*)(wh + ch);
    const float2 bhv = *(const float2*)(bh + ch);
    float l0 = 0.f, l1 = 0.f;
#pragma unroll
    for (int mm = 0; mm < 4; ++mm) {
        const int cl = mm >> 1, m = mm & 1;
        __syncthreads();
#pragma unroll
        for (int j = 0; j < 8; ++j) {
            const int col = wid * 128 + j * 16 + (lane & 15);
#pragma unroll
            for (int r4 = 0; r4 < 4; ++r4)
                U[((lane >> 4) * 4 + r4) * USTRIDE + col] = acc[mm][j][r4];
        }
        __syncthreads();
        for (int tl = 0; tl < 16; ++tl) {
            const float2 u = *(const float2*)&U[tl * USTRIDE + ch];
            l0 = fmaf(l0, whv.x, u.x + bhv.x);
            l1 = fmaf(l1, whv.y, u.y + bhv.y);
            const int t = (c0 + cl) * CHUNK + m * 16 + tl;
            float2 o; o.x = l0; o.y = l1;
            *(float2*)(out + ((size_t)t * BATCH + b) * DLAT + ch) = o;
        }
        if (m == 1) {
            float2 fo; fo.x = l0; fo.y = l1;
            *(float2*)(F + ((size_t)(c0 + cl) * BATCH + b) * DLAT + ch) = fo;
            l0 = 0.f; l1 = 0.f;
        }
    }
}

__global__ __launch_bounds__(128) void rnn_prefix(
    const float* __restrict__ h0, const float* __restrict__ wh,
    const float* __restrict__ F, float* __restrict__ Hpre)
{
    const int b  = blockIdx.x;
    const int j4 = threadIdx.x * 4;
    const size_t cb = (size_t)b * DLAT + j4;
    float4 w4 = *(const float4*)(wh + j4);
    float wv[4] = {w4.x, w4.y, w4.z, w4.w};
    float wc[4];
#pragma unroll
    for (int k = 0; k < 4; ++k) wc[k] = pow32(wv[k]);
    float4 h4 = *(const float4*)(h0 + cb);
    float Hv[4] = {h4.x, h4.y, h4.z, h4.w};
    for (int cg = 0; cg < NCHUNK / 4; ++cg) {
        float4 Fv[4];
#pragma unroll
        for (int i = 0; i < 4; ++i)
            Fv[i] = *(const float4*)(F + (size_t)(cg * 4 + i) * (BATCH * DLAT) + cb);
#pragma unroll
        for (int i = 0; i < 4; ++i) {
            float4 o = {Hv[0], Hv[1], Hv[2], Hv[3]};
            *(float4*)(Hpre + (size_t)(cg * 4 + i) * (BATCH * DLAT) + cb) = o;
            Hv[0] = fmaf(Hv[0], wc[0], Fv[i].x);
            Hv[1] = fmaf(Hv[1], wc[1], Fv[i].y);
            Hv[2] = fmaf(Hv[2], wc[2], Fv[i].z);
            Hv[3] = fmaf(Hv[3], wc[3], Fv[i].w);
        }
    }
}

__global__ __launch_bounds__(256) void rnn_fix2(
    const float* __restrict__ wh, const float* __restrict__ Hpre,
    float* __restrict__ out)
{
    const int tid = threadIdx.x;
    const int c   = blockIdx.x * 2 + (tid >> 7);
    const int b   = blockIdx.y;
    const int j4  = (tid & 127) * 4;
    const size_t cb = (size_t)b * DLAT + j4;
    float4 w4 = *(const float4*)(wh + j4);
    float4 H4 = *(const float4*)(Hpre + (size_t)c * (BATCH * DLAT) + cb);
    float wv[4] = {w4.x, w4.y, w4.z, w4.w};
    float Hv[4] = {H4.x, H4.y, H4.z, H4.w};
    float sc[4] = {wv[0], wv[1], wv[2], wv[3]};
#pragma unroll 4
    for (int d = 0; d < CHUNK; ++d) {
        const size_t off = ((size_t)(c * CHUNK + d) * BATCH + b) * DLAT + j4;
        float4 l4 = *(const float4*)(out + off);
        float4 res;
        res.x = tanhf(fmaf(sc[0], Hv[0], l4.x));
        res.y = tanhf(fmaf(sc[1], Hv[1], l4.y));
        res.z = tanhf(fmaf(sc[2], Hv[2], l4.z));
        res.w = tanhf(fmaf(sc[3], Hv[3], l4.w));
        *(float4*)(out + off) = res;
        sc[0] *= wv[0]; sc[1] *= wv[1]; sc[2] *= wv[2]; sc[3] *= wv[3];
    }
}

extern "C" void kernel_launch(void* const* d_in, const int* in_sizes, int n_in,
                              void* d_out, int out_size, void* d_ws, size_t ws_size,
                              hipStream_t stream) {
    const float* X  = (const float*)d_in[0];
    const float* h0 = (const float*)d_in[1];
    const float* wx = (const float*)d_in[2];
    const float* wh = (const float*)d_in[3];
    const float* bh = (const float*)d_in[4];
    float* out = (float*)d_out;

    const size_t seg = (size_t)NCHUNK * BATCH * DLAT;   // 2M floats = 8 MiB
    const size_t wxt_elems = 4 * 32 * 64 * 8;           // 65536 ushorts = 128 KB

    // Fused layout: [counter 64B][flags 16KB][pad->32KB][F 8MB][Hincl 8MB][wxt 3x128KB]
    char* wsb = (char*)d_ws;
    int*   counter = (int*)wsb;
    int*   flags   = (int*)(wsb + 64);
    float* Ff      = (float*)(wsb + 32768);
    float* Hincl   = Ff + seg;
    unsigned short* fwxtH = (unsigned short*)(Hincl + seg);
    unsigned short* fwxtM = fwxtH + wxt_elems;
    unsigned short* fwxtL = fwxtM + wxt_elems;
    const size_t need_fused = 32768 + 2 * seg * 4 + 3 * wxt_elems * 2;  // ~16.8 MiB

    if (ws_size >= need_fused) {
        hipMemsetAsync(d_ws, 0, 64 + NITEMS * sizeof(int), stream);
        wx_transform<<<dim3(32), dim3(256), 0, stream>>>(wx, fwxtH, fwxtM, fwxtL);
        rnn_fused2<<<dim3(NITEMS), dim3(256), 0, stream>>>(
            X, fwxtH, fwxtM, fwxtL, h0, wh, bh, out, counter, flags, Ff, Hincl);
        return;
    }

    // Fallback: R16 3-kernel path.
    float* F = (float*)d_ws;
    unsigned short* wxtH = (unsigned short*)(F + seg);
    unsigned short* wxtM = wxtH + wxt_elems;
    unsigned short* wxtL = wxtM + wxt_elems;
    float* Hpre = (float*)(wxtL + wxt_elems);
    wx_transform<<<dim3(32), dim3(256), 0, stream>>>(wx, wxtH, wxtM, wxtL);
    rnn_local_mfma2<<<dim3(NCHUNK / 2, BATCH), dim3(256), 0, stream>>>(
        X, wxtH, wxtM, wxtL, wh, bh, out, F);
    rnn_prefix<<<dim3(BATCH), dim3(128), 0, stream>>>(h0, wh, F, Hpre);
    rnn_fix2<<<dim3(NCHUNK / 2, BATCH), dim3(256), 0, stream>>>(wh, Hpre, out);
}

// Round 18
// 565.931 us; speedup vs baseline: 2.6271x; 2.6271x over previous
//
#include <hip/hip_runtime.h>
#include <cstdint>
#include <cstddef>

#define L_SEQ 4096
#define BATCH 32
#define DIN 128
#define DLAT 512
#define CHUNK 32
#define NCHUNK (L_SEQ / CHUNK)   // 128

typedef __attribute__((ext_vector_type(8))) short short8;
typedef __attribute__((ext_vector_type(4))) float f32x4;

// 3-way Dekker-style split: x = h + m + l + r, |r| <= 2^-27 |x|.
__device__ __forceinline__ unsigned short bf16rne(float x) {
    unsigned int b = __builtin_bit_cast(unsigned int, x);
    unsigned int r = b + 0x7FFFu + ((b >> 16) & 1u);
    return (unsigned short)(r >> 16);
}
__device__ __forceinline__ float bf16tof(unsigned short h) {
    return __builtin_bit_cast(float, (unsigned int)h << 16);
}
__device__ __forceinline__ void bf16split3(float x, unsigned short& h,
                                           unsigned short& m, unsigned short& l) {
    h = bf16rne(x);
    float r1 = x - bf16tof(h);
    m = bf16rne(r1);
    float r2 = r1 - bf16tof(m);
    l = bf16rne(r2);
}

// ---------------------------------------------------------------------------
// Kernel W: wx [128][512] fp32 -> MFMA B-frag layout, bf16 h/m/l (3x128 KB).
// Frag fid = kt*32 + nt; lane holds col n = nt*16+(lane&15), k = kt*32+(lane>>4)*8+i.
// ---------------------------------------------------------------------------
__global__ __launch_bounds__(256) void wx_transform(
    const float* __restrict__ wx,
    unsigned short* __restrict__ wxtH,
    unsigned short* __restrict__ wxtM,
    unsigned short* __restrict__ wxtL)
{
    const int gid  = blockIdx.x * 256 + threadIdx.x;
    const int fid  = gid >> 6;
    const int lane = gid & 63;
    const int kt = fid >> 5, nt = fid & 31;
    const int n  = nt * 16 + (lane & 15);
    const int kb = kt * 32 + (lane >> 4) * 8;

    short8 h8, m8, l8;
#pragma unroll
    for (int i = 0; i < 8; ++i) {
        unsigned short h, m, l;
        bf16split3(wx[(size_t)(kb + i) * DLAT + n], h, m, l);
        h8[i] = (short)h; m8[i] = (short)m; l8[i] = (short)l;
    }
    ((short8*)wxtH)[fid * 64 + lane] = h8;
    ((short8*)wxtM)[fid * 64 + lane] = m8;
    ((short8*)wxtL)[fid * 64 + lane] = l8;
}

// ---------------------------------------------------------------------------
// SEQUENTIAL-PER-BLOCK kernel: block = (jg, b) owns batch b x channels
// [jg*32, jg*32+32) and marches over ALL 128 chunks sequentially.
// The scan NEVER crosses a block -> no flags, no F/Hpre, no fix2, no 512 MB
// out round-trip, no cross-XCD atomics (R15/R17's 1.3 ms fabric-contention tax).
// Per chunk: stage X->AF (3-way bf16 split, 24 KB) -> per-wave MFMA on its
// (m-tile, j-frag) with B-frags held in REGISTERS (loaded once per block;
// kills the 1.5 GB wxt L2 re-read) -> U[32][36] -> wave-0 scan (exact
// reference recurrence order, h in registers) -> tanh -> single out write.
// grid (16, 32) = 512 blocks x 256 thr = 2 blocks/CU, all co-resident.
// ---------------------------------------------------------------------------
__global__ __launch_bounds__(256) void rnn_seq(
    const float* __restrict__ X,          // [L, B, DIN]
    const unsigned short* __restrict__ wxtH,
    const unsigned short* __restrict__ wxtM,
    const unsigned short* __restrict__ wxtL,
    const float* __restrict__ h0,         // [B, DLAT]
    const float* __restrict__ wh,         // [DLAT]
    const float* __restrict__ bh,         // [DLAT]
    float* __restrict__ out)              // [L, B, DLAT]
{
    __shared__ __align__(16) unsigned short AF[8 * 3 * 64 * 8];  // 24 KB
    __shared__ float U[CHUNK][36];                               // 4.6 KB, 36: bank-spread

    const int tid  = threadIdx.x;
    const int wid  = tid >> 6, lane = tid & 63;
    const int jg   = blockIdx.x;          // 0..15 channel-group (32 ch)
    const int b    = blockIdx.y;          // 0..31 batch
    const int m    = wid & 1;             // wave's m-tile (timestep half)
    const int jloc = wid >> 1;            // wave's j-frag within group (0..1)
    const int nt   = jg * 2 + jloc;       // global 16-col frag index (0..31)

    // B-fragments in registers, loaded ONCE per block (12 short8 = 48 VGPR).
    short8 Bh[4], Bm[4], Bl[4];
#pragma unroll
    for (int kt = 0; kt < 4; ++kt) {
        const int idx = (kt * 32 + nt) * 64 + lane;
        Bh[kt] = ((const short8*)wxtH)[idx];
        Bm[kt] = ((const short8*)wxtM)[idx];
        Bl[kt] = ((const short8*)wxtL)[idx];
    }

    // Scan state (used by wave 0 lanes 0-31; computed uniformly, in-bounds).
    const int chs = jg * 32 + (lane & 31);
    const float whc = wh[chs];
    const float bhc = bh[chs];
    float hreg = h0[(size_t)b * DLAT + chs];

    for (int c = 0; c < NCHUNK; ++c) {
        // ---- Stage: X chunk -> regs -> bf16 h/m/l -> AF (2 slots/thread) ----
#pragma unroll
        for (int sl = 0; sl < 2; ++sl) {
            const int slot = tid + sl * 256;
            const int f  = slot >> 6;          // (mS*4 + ktS), 0..7
            const int ls = slot & 63;
            const int mS = f >> 2, ktS = f & 3;
            const int t  = c * CHUNK + mS * 16 + (ls & 15);
            const int kb = ktS * 32 + (ls >> 4) * 8;
            const float* p = X + ((size_t)t * BATCH + b) * DIN + kb;
            const float4 va = *(const float4*)p;
            const float4 vb = *(const float4*)(p + 4);
            float v[8] = {va.x, va.y, va.z, va.w, vb.x, vb.y, vb.z, vb.w};
            short8 h8, m8, l8;
#pragma unroll
            for (int i = 0; i < 8; ++i) {
                unsigned short h, mm, l;
                bf16split3(v[i], h, mm, l);
                h8[i] = (short)h; m8[i] = (short)mm; l8[i] = (short)l;
            }
            ((short8*)AF)[(f * 3 + 0) * 64 + ls] = h8;
            ((short8*)AF)[(f * 3 + 1) * 64 + ls] = m8;
            ((short8*)AF)[(f * 3 + 2) * 64 + ls] = l8;
        }
        __syncthreads();

        // ---- MFMA: this wave's (m, jloc). 6-product emulation, smallest-first. ----
        f32x4 acc = (f32x4){0.f, 0.f, 0.f, 0.f};
#pragma unroll
        for (int kt = 0; kt < 4; ++kt) {
            const short8 ah = ((const short8*)AF)[((m * 4 + kt) * 3 + 0) * 64 + lane];
            const short8 am = ((const short8*)AF)[((m * 4 + kt) * 3 + 1) * 64 + lane];
            const short8 al = ((const short8*)AF)[((m * 4 + kt) * 3 + 2) * 64 + lane];
            acc = __builtin_amdgcn_mfma_f32_16x16x32_bf16(am, Bm[kt], acc, 0, 0, 0);
            acc = __builtin_amdgcn_mfma_f32_16x16x32_bf16(al, Bh[kt], acc, 0, 0, 0);
            acc = __builtin_amdgcn_mfma_f32_16x16x32_bf16(ah, Bl[kt], acc, 0, 0, 0);
            acc = __builtin_amdgcn_mfma_f32_16x16x32_bf16(am, Bh[kt], acc, 0, 0, 0);
            acc = __builtin_amdgcn_mfma_f32_16x16x32_bf16(ah, Bm[kt], acc, 0, 0, 0);
            acc = __builtin_amdgcn_mfma_f32_16x16x32_bf16(ah, Bh[kt], acc, 0, 0, 0);
        }
        // D layout (m89-verified): col = lane&15 (channel), row = (lane>>4)*4+reg (t).
#pragma unroll
        for (int r4 = 0; r4 < 4; ++r4)
            U[m * 16 + (lane >> 4) * 4 + r4][jloc * 16 + (lane & 15)] = acc[r4];
        __syncthreads();

        // ---- Scan: wave 0, lanes 0-31, exact reference order; tanh off-chain. ----
        if (wid == 0 && lane < 32) {
            float u[CHUNK];
#pragma unroll
            for (int t = 0; t < CHUNK; ++t)
                u[t] = U[t][lane];
            const size_t obase = ((size_t)(c * CHUNK) * BATCH + b) * DLAT + jg * 32 + lane;
#pragma unroll
            for (int t = 0; t < CHUNK; ++t) {
                hreg = fmaf(hreg, whc, u[t] + bhc);
                out[obase + (size_t)t * (BATCH * DLAT)] = tanhf(hreg);
            }
        }
        __syncthreads();   // U consumed before next chunk overwrites
    }
}

extern "C" void kernel_launch(void* const* d_in, const int* in_sizes, int n_in,
                              void* d_out, int out_size, void* d_ws, size_t ws_size,
                              hipStream_t stream) {
    const float* X  = (const float*)d_in[0];
    const float* h0 = (const float*)d_in[1];
    const float* wx = (const float*)d_in[2];
    const float* wh = (const float*)d_in[3];
    const float* bh = (const float*)d_in[4];
    float* out = (float*)d_out;

    const size_t wxt_elems = 4 * 32 * 64 * 8;           // 65536 ushorts = 128 KB
    unsigned short* wxtH = (unsigned short*)d_ws;
    unsigned short* wxtM = wxtH + wxt_elems;
    unsigned short* wxtL = wxtM + wxt_elems;
    // needs only 384 KB of ws (harness provides >= 16 MB per prior rounds)

    wx_transform<<<dim3(32), dim3(256), 0, stream>>>(wx, wxtH, wxtM, wxtL);
    rnn_seq<<<dim3(16, BATCH), dim3(256), 0, stream>>>(
        X, wxtH, wxtM, wxtL, h0, wh, bh, out);
}

// Round 19
// 263.190 us; speedup vs baseline: 5.6491x; 2.1503x over previous
//
#include <hip/hip_runtime.h>
#include <cstdint>
#include <cstddef>

#define L_SEQ 4096
#define BATCH 32
#define DIN 128
#define DLAT 512
#define CHUNK 32
#define NCHUNK (L_SEQ / CHUNK)   // 128

typedef __attribute__((ext_vector_type(8))) short short8;
typedef __attribute__((ext_vector_type(4))) float f32x4;

__device__ __forceinline__ unsigned short bf16rne(float x) {
    unsigned int b = __builtin_bit_cast(unsigned int, x);
    unsigned int r = b + 0x7FFFu + ((b >> 16) & 1u);
    return (unsigned short)(r >> 16);
}
__device__ __forceinline__ float bf16tof(unsigned short h) {
    return __builtin_bit_cast(float, (unsigned int)h << 16);
}
__device__ __forceinline__ void bf16split3(float x, unsigned short& h,
                                           unsigned short& m, unsigned short& l) {
    h = bf16rne(x);
    float r1 = x - bf16tof(h);
    m = bf16rne(r1);
    float r2 = r1 - bf16tof(m);
    l = bf16rne(r2);
}
__device__ __forceinline__ float pow32(float x) {
    float t = x;
    t = t * t; t = t * t; t = t * t; t = t * t; t = t * t;
    return t;
}
__device__ __forceinline__ float bpermf(int idxb, float v) {
    return __builtin_bit_cast(float,
        __builtin_amdgcn_ds_bpermute(idxb, __builtin_bit_cast(int, v)));
}

// ---------------------------------------------------------------------------
// Kernel W: wx [128][512] fp32 -> MFMA B-frag layout, bf16 h/m/l (3x128 KB).
// ---------------------------------------------------------------------------
__global__ __launch_bounds__(256) void wx_transform(
    const float* __restrict__ wx,
    unsigned short* __restrict__ wxtH,
    unsigned short* __restrict__ wxtM,
    unsigned short* __restrict__ wxtL)
{
    const int gid  = blockIdx.x * 256 + threadIdx.x;
    const int fid  = gid >> 6;
    const int lane = gid & 63;
    const int kt = fid >> 5, nt = fid & 31;
    const int n  = nt * 16 + (lane & 15);
    const int kb = kt * 32 + (lane >> 4) * 8;

    short8 h8, m8, l8;
#pragma unroll
    for (int i = 0; i < 8; ++i) {
        unsigned short h, m, l;
        bf16split3(wx[(size_t)(kb + i) * DLAT + n], h, m, l);
        h8[i] = (short)h; m8[i] = (short)m; l8[i] = (short)l;
    }
    ((short8*)wxtH)[fid * 64 + lane] = h8;
    ((short8*)wxtM)[fid * 64 + lane] = m8;
    ((short8*)wxtL)[fid * 64 + lane] = l8;
}

// ---------------------------------------------------------------------------
// Kernel A3: R14's GEMM, but the chunk-local scan runs ENTIRELY IN REGISTERS
// on the MFMA D-layout (col=lane&15, row=(lane>>4)*4+reg):
//   per (m,j): exact 4-step serial segment scan per lane-group ->
//   Kogge-Stone across 4 lane-groups via ds_bpermute (scales w^4, w^8) ->
//   exclusive init He -> h_r = p_r + w^{r+1}*He (same form as fix2) ->
//   direct locals write. m0->m1 chained by one broadcast (h15).
// Deletes the U buffer (LDS 33.4->24.6 KB), 2 of 3 barriers, ~96 LDS
// ops/thread. grid (NCHUNK, BATCH) = 4096 blocks, 256 threads.
// ---------------------------------------------------------------------------
__global__ __launch_bounds__(256) void rnn_local_mfma3(
    const float* __restrict__ X,          // [L, B, DIN]
    const unsigned short* __restrict__ wxtH,
    const unsigned short* __restrict__ wxtM,
    const unsigned short* __restrict__ wxtL,
    const float* __restrict__ wh,         // [DLAT]
    const float* __restrict__ bh,         // [DLAT]
    float* __restrict__ out,              // [L, B, DLAT] pre-tanh locals
    float* __restrict__ F)                // [NCHUNK, B, DLAT]
{
    __shared__ __align__(16) unsigned short AF[8 * 3 * 64 * 8];  // 24 KB only

    const int tid  = threadIdx.x;
    const int c = blockIdx.x, b = blockIdx.y;
    const int wid = tid >> 6, lane = tid & 63;
    const int g = lane >> 4;
    const int col = lane & 15;

    // ---- Phase S: stage + 3-way convert into AF ----
#pragma unroll
    for (int sl = 0; sl < 2; ++sl) {
        const int slot = tid + sl * 256;
        const int f  = slot >> 6;
        const int ls = slot & 63;
        const int mS = f >> 2, kt = f & 3;
        const int t  = c * CHUNK + mS * 16 + (ls & 15);
        const int kb = kt * 32 + (ls >> 4) * 8;
        const float* p = X + ((size_t)t * BATCH + b) * DIN + kb;
        const float4 va = *(const float4*)p;
        const float4 vb = *(const float4*)(p + 4);
        float v[8] = {va.x, va.y, va.z, va.w, vb.x, vb.y, vb.z, vb.w};
        short8 h8, m8, l8;
#pragma unroll
        for (int i = 0; i < 8; ++i) {
            unsigned short h, mm, l;
            bf16split3(v[i], h, mm, l);
            h8[i] = (short)h; m8[i] = (short)mm; l8[i] = (short)l;
        }
        ((short8*)AF)[(f * 3 + 0) * 64 + ls] = h8;
        ((short8*)AF)[(f * 3 + 1) * 64 + ls] = m8;
        ((short8*)AF)[(f * 3 + 2) * 64 + ls] = l8;
    }

    // wh/bh for this lane's 8 channels (overlaps with staging latency)
    float whj[8], bhj[8];
#pragma unroll
    for (int j = 0; j < 8; ++j) {
        const int chj = wid * 128 + j * 16 + col;
        whj[j] = wh[chj];
        bhj[j] = bh[chj];
    }
    __syncthreads();

    // ---- Phase M: 6-product MFMA emulation -> acc[2][8] ----
    f32x4 acc[2][8];
#pragma unroll
    for (int m = 0; m < 2; ++m)
#pragma unroll
        for (int j = 0; j < 8; ++j)
            acc[m][j] = (f32x4){0.f, 0.f, 0.f, 0.f};

    const short8* AFv = (const short8*)AF;
    const short8* BHp = (const short8*)wxtH;
    const short8* BMp = (const short8*)wxtM;
    const short8* BLp = (const short8*)wxtL;

#pragma unroll
    for (int kt = 0; kt < 4; ++kt) {
        const short8 a0h = AFv[((0 * 4 + kt) * 3 + 0) * 64 + lane];
        const short8 a0m = AFv[((0 * 4 + kt) * 3 + 1) * 64 + lane];
        const short8 a0l = AFv[((0 * 4 + kt) * 3 + 2) * 64 + lane];
        const short8 a1h = AFv[((1 * 4 + kt) * 3 + 0) * 64 + lane];
        const short8 a1m = AFv[((1 * 4 + kt) * 3 + 1) * 64 + lane];
        const short8 a1l = AFv[((1 * 4 + kt) * 3 + 2) * 64 + lane];
#pragma unroll
        for (int j = 0; j < 8; ++j) {
            const int idx = (kt * 32 + wid * 8 + j) * 64 + lane;
            const short8 bh8 = BHp[idx];
            const short8 bm8 = BMp[idx];
            const short8 bl8 = BLp[idx];
            acc[0][j] = __builtin_amdgcn_mfma_f32_16x16x32_bf16(a0m, bm8, acc[0][j], 0, 0, 0);
            acc[0][j] = __builtin_amdgcn_mfma_f32_16x16x32_bf16(a0l, bh8, acc[0][j], 0, 0, 0);
            acc[0][j] = __builtin_amdgcn_mfma_f32_16x16x32_bf16(a0h, bl8, acc[0][j], 0, 0, 0);
            acc[0][j] = __builtin_amdgcn_mfma_f32_16x16x32_bf16(a0m, bh8, acc[0][j], 0, 0, 0);
            acc[0][j] = __builtin_amdgcn_mfma_f32_16x16x32_bf16(a0h, bm8, acc[0][j], 0, 0, 0);
            acc[0][j] = __builtin_amdgcn_mfma_f32_16x16x32_bf16(a0h, bh8, acc[0][j], 0, 0, 0);
            acc[1][j] = __builtin_amdgcn_mfma_f32_16x16x32_bf16(a1m, bm8, acc[1][j], 0, 0, 0);
            acc[1][j] = __builtin_amdgcn_mfma_f32_16x16x32_bf16(a1l, bh8, acc[1][j], 0, 0, 0);
            acc[1][j] = __builtin_amdgcn_mfma_f32_16x16x32_bf16(a1h, bl8, acc[1][j], 0, 0, 0);
            acc[1][j] = __builtin_amdgcn_mfma_f32_16x16x32_bf16(a1m, bh8, acc[1][j], 0, 0, 0);
            acc[1][j] = __builtin_amdgcn_mfma_f32_16x16x32_bf16(a1h, bm8, acc[1][j], 0, 0, 0);
            acc[1][j] = __builtin_amdgcn_mfma_f32_16x16x32_bf16(a1h, bh8, acc[1][j], 0, 0, 0);
        }
    }

    // ---- In-register scan + locals write. No barriers, no U buffer. ----
    const int i16 = ((lane - 16) & 63) << 2;
    const int i32 = ((lane - 32) & 63) << 2;
    const int i48 = (col + 48) << 2;
    const size_t BD = (size_t)BATCH * DLAT;

#pragma unroll
    for (int j = 0; j < 8; ++j) {
        const float w  = whj[j], bb = bhj[j];
        const float w2 = w * w, w3 = w2 * w, w4 = w2 * w2, w8 = w4 * w4;
        float h15 = 0.f, hlast = 0.f;
#pragma unroll
        for (int m = 0; m < 2; ++m) {
            // Exact serial partials within lane-group (init 0)
            const float u0 = acc[m][j][0] + bb;
            const float u1 = acc[m][j][1] + bb;
            const float u2 = acc[m][j][2] + bb;
            const float u3 = acc[m][j][3] + bb;
            const float p0 = u0;
            const float p1 = fmaf(p0, w, u1);
            const float p2 = fmaf(p1, w, u2);
            const float p3 = fmaf(p2, w, u3);
            // Kogge-Stone inclusive over 4 lane-groups (segment finals p3)
            const float t1 = bpermf(i16, p3);
            const float f1 = (g >= 1) ? fmaf(w4, t1, p3) : p3;
            const float t2 = bpermf(i32, f1);
            const float f2 = (g >= 2) ? fmaf(w8, t2, f1) : f1;
            // Exclusive prefix for this group
            const float pe = bpermf(i16, f2);
            float He = (g >= 1) ? pe : 0.0f;
            if (m == 1) {
                const float w4g = (g == 0) ? 1.0f : (g == 1) ? w4
                                 : (g == 2) ? w8 : w4 * w8;
                He = fmaf(w4g, h15, He);
            }
            // h_r = p_r + w^{r+1} * He  (same algebraic form as fix2)
            const float h0v = fmaf(w,  He, p0);
            const float h1v = fmaf(w2, He, p1);
            const float h2v = fmaf(w3, He, p2);
            const float h3v = fmaf(w4, He, p3);
            const size_t base = ((size_t)(c * CHUNK + m * 16 + g * 4) * BATCH + b) * DLAT
                                + wid * 128 + j * 16 + col;
            out[base]          = h0v;
            out[base + BD]     = h1v;
            out[base + 2 * BD] = h2v;
            out[base + 3 * BD] = h3v;
            if (m == 0) {
                h15 = bpermf(i48, f2);   // broadcast inclusive end (group 3)
            } else {
                hlast = h3v;             // valid at g==3: h at t=31
            }
        }
        if (g == 3)
            F[((size_t)c * BATCH + b) * DLAT + wid * 128 + j * 16 + col] = hlast;
    }
}

// ---------------------------------------------------------------------------
// Kernel B0: sequential prefix -> Hpre[c]. grid (BATCH), block 128.
// ---------------------------------------------------------------------------
__global__ __launch_bounds__(128) void rnn_prefix(
    const float* __restrict__ h0, const float* __restrict__ wh,
    const float* __restrict__ F, float* __restrict__ Hpre)
{
    const int b  = blockIdx.x;
    const int j4 = threadIdx.x * 4;
    const size_t cb = (size_t)b * DLAT + j4;
    float4 w4 = *(const float4*)(wh + j4);
    float wv[4] = {w4.x, w4.y, w4.z, w4.w};
    float wc[4];
#pragma unroll
    for (int k = 0; k < 4; ++k) wc[k] = pow32(wv[k]);
    float4 h4 = *(const float4*)(h0 + cb);
    float Hv[4] = {h4.x, h4.y, h4.z, h4.w};
    for (int cg = 0; cg < NCHUNK / 4; ++cg) {
        float4 Fv[4];
#pragma unroll
        for (int i = 0; i < 4; ++i)
            Fv[i] = *(const float4*)(F + (size_t)(cg * 4 + i) * (BATCH * DLAT) + cb);
#pragma unroll
        for (int i = 0; i < 4; ++i) {
            float4 o = {Hv[0], Hv[1], Hv[2], Hv[3]};
            *(float4*)(Hpre + (size_t)(cg * 4 + i) * (BATCH * DLAT) + cb) = o;
            Hv[0] = fmaf(Hv[0], wc[0], Fv[i].x);
            Hv[1] = fmaf(Hv[1], wc[1], Fv[i].y);
            Hv[2] = fmaf(Hv[2], wc[2], Fv[i].z);
            Hv[3] = fmaf(Hv[3], wc[3], Fv[i].w);
        }
    }
}

// ---------------------------------------------------------------------------
// Kernel C: streaming fixup out_t = tanh(l_t + wh^{d+1} * Hpre[c]).
// ---------------------------------------------------------------------------
__global__ __launch_bounds__(256) void rnn_fix2(
    const float* __restrict__ wh, const float* __restrict__ Hpre,
    float* __restrict__ out)
{
    const int tid = threadIdx.x;
    const int c   = blockIdx.x * 2 + (tid >> 7);
    const int b   = blockIdx.y;
    const int j4  = (tid & 127) * 4;
    const size_t cb = (size_t)b * DLAT + j4;
    float4 w4 = *(const float4*)(wh + j4);
    float4 H4 = *(const float4*)(Hpre + (size_t)c * (BATCH * DLAT) + cb);
    float wv[4] = {w4.x, w4.y, w4.z, w4.w};
    float Hv[4] = {H4.x, H4.y, H4.z, H4.w};
    float sc[4] = {wv[0], wv[1], wv[2], wv[3]};
#pragma unroll 4
    for (int d = 0; d < CHUNK; ++d) {
        const size_t off = ((size_t)(c * CHUNK + d) * BATCH + b) * DLAT + j4;
        float4 l4 = *(const float4*)(out + off);
        float4 res;
        res.x = tanhf(fmaf(sc[0], Hv[0], l4.x));
        res.y = tanhf(fmaf(sc[1], Hv[1], l4.y));
        res.z = tanhf(fmaf(sc[2], Hv[2], l4.z));
        res.w = tanhf(fmaf(sc[3], Hv[3], l4.w));
        *(float4*)(out + off) = res;
        sc[0] *= wv[0]; sc[1] *= wv[1]; sc[2] *= wv[2]; sc[3] *= wv[3];
    }
}

// Fallback fixup (ws too small for Hpre): fold H per block from F.
__global__ __launch_bounds__(256) void rnn_fix(
    const float* __restrict__ h0, const float* __restrict__ wh,
    const float* __restrict__ F, float* __restrict__ out)
{
    const int tid = threadIdx.x;
    const int c   = blockIdx.x * 2 + (tid >> 7);
    const int b   = blockIdx.y;
    const int j4  = (tid & 127) * 4;
    const size_t cb = (size_t)b * DLAT + j4;
    float4 h4 = *(const float4*)(h0 + cb);
    float4 w4 = *(const float4*)(wh + j4);
    float Hv[4] = {h4.x, h4.y, h4.z, h4.w};
    float wv[4] = {w4.x, w4.y, w4.z, w4.w};
    float wc[4];
#pragma unroll
    for (int k = 0; k < 4; ++k) wc[k] = pow32(wv[k]);
    for (int cc = 0; cc < c; ++cc) {
        const float4 Fv = *(const float4*)(F + ((size_t)cc * BATCH + b) * DLAT + j4);
        Hv[0] = fmaf(Hv[0], wc[0], Fv.x);
        Hv[1] = fmaf(Hv[1], wc[1], Fv.y);
        Hv[2] = fmaf(Hv[2], wc[2], Fv.z);
        Hv[3] = fmaf(Hv[3], wc[3], Fv.w);
    }
    float sc[4] = {wv[0], wv[1], wv[2], wv[3]};
    for (int d = 0; d < CHUNK; ++d) {
        const size_t off = ((size_t)(c * CHUNK + d) * BATCH + b) * DLAT + j4;
        float4 l4 = *(const float4*)(out + off);
        float4 res;
        res.x = tanhf(fmaf(sc[0], Hv[0], l4.x));
        res.y = tanhf(fmaf(sc[1], Hv[1], l4.y));
        res.z = tanhf(fmaf(sc[2], Hv[2], l4.z));
        res.w = tanhf(fmaf(sc[3], Hv[3], l4.w));
        *(float4*)(out + off) = res;
        sc[0] *= wv[0]; sc[1] *= wv[1]; sc[2] *= wv[2]; sc[3] *= wv[3];
    }
}

extern "C" void kernel_launch(void* const* d_in, const int* in_sizes, int n_in,
                              void* d_out, int out_size, void* d_ws, size_t ws_size,
                              hipStream_t stream) {
    const float* X  = (const float*)d_in[0];
    const float* h0 = (const float*)d_in[1];
    const float* wx = (const float*)d_in[2];
    const float* wh = (const float*)d_in[3];
    const float* bh = (const float*)d_in[4];
    float* out = (float*)d_out;

    const size_t seg = (size_t)NCHUNK * BATCH * DLAT;   // 2M floats = 8 MiB
    const size_t wxt_elems = 4 * 32 * 64 * 8;           // 65536 ushorts = 128 KB
    float* F = (float*)d_ws;
    unsigned short* wxtH = (unsigned short*)(F + seg);
    unsigned short* wxtM = wxtH + wxt_elems;
    unsigned short* wxtL = wxtM + wxt_elems;
    float* Hpre = (float*)(wxtL + wxt_elems);

    const size_t need_full = seg * 4 + wxt_elems * 3 * 2 + seg * 4;  // 16.375 MiB

    wx_transform<<<dim3(32), dim3(256), 0, stream>>>(wx, wxtH, wxtM, wxtL);
    rnn_local_mfma3<<<dim3(NCHUNK, BATCH), dim3(256), 0, stream>>>(
        X, wxtH, wxtM, wxtL, wh, bh, out, F);
    if (ws_size >= need_full) {
        rnn_prefix<<<dim3(BATCH), dim3(128), 0, stream>>>(h0, wh, F, Hpre);
        rnn_fix2<<<dim3(NCHUNK / 2, BATCH), dim3(256), 0, stream>>>(wh, Hpre, out);
    } else {
        rnn_fix<<<dim3(NCHUNK / 2, BATCH), dim3(256), 0, stream>>>(h0, wh, F, out);
    }
}

// Round 21
// 230.431 us; speedup vs baseline: 6.4522x; 1.1422x over previous
//
#include <hip/hip_runtime.h>
#include <cstdint>
#include <cstddef>

#define L_SEQ 4096
#define BATCH 32
#define DIN 128
#define DLAT 512
#define CHUNK 32
#define NCHUNK (L_SEQ / CHUNK)   // 128
#define USTRIDE 522              // (4*522)%32==8 -> row-groups on banks {0,8,16,24}: 2-way max

typedef __attribute__((ext_vector_type(8))) short short8;
typedef __attribute__((ext_vector_type(4))) float f32x4;

// 3-way Dekker-style split: x = h + m + l + r, |r| <= 2^-27 |x|.
__device__ __forceinline__ unsigned short bf16rne(float x) {
    unsigned int b = __builtin_bit_cast(unsigned int, x);
    unsigned int r = b + 0x7FFFu + ((b >> 16) & 1u);
    return (unsigned short)(r >> 16);
}
__device__ __forceinline__ float bf16tof(unsigned short h) {
    return __builtin_bit_cast(float, (unsigned int)h << 16);
}
__device__ __forceinline__ void bf16split3(float x, unsigned short& h,
                                           unsigned short& m, unsigned short& l) {
    h = bf16rne(x);
    float r1 = x - bf16tof(h);
    m = bf16rne(r1);
    float r2 = r1 - bf16tof(m);
    l = bf16rne(r2);
}

// ---------------------------------------------------------------------------
// Kernel W: one-time transform of wx [128][512] fp32 into MFMA B-fragment
// layout, bf16 h/m/l. Frag fid = kt*32 + nt; lane holds col n = nt*16+(lane&15),
// k = kt*32 + (lane>>4)*8 + i. 3 x 128 KB into ws.
// ---------------------------------------------------------------------------
__global__ __launch_bounds__(256) void wx_transform(
    const float* __restrict__ wx,
    unsigned short* __restrict__ wxtH,
    unsigned short* __restrict__ wxtM,
    unsigned short* __restrict__ wxtL)
{
    const int gid  = blockIdx.x * 256 + threadIdx.x;  // 8192 threads
    const int fid  = gid >> 6;        // 0..127
    const int lane = gid & 63;
    const int kt = fid >> 5, nt = fid & 31;
    const int n  = nt * 16 + (lane & 15);
    const int kb = kt * 32 + (lane >> 4) * 8;

    short8 h8, m8, l8;
#pragma unroll
    for (int i = 0; i < 8; ++i) {
        unsigned short h, m, l;
        bf16split3(wx[(size_t)(kb + i) * DLAT + n], h, m, l);
        h8[i] = (short)h; m8[i] = (short)m; l8[i] = (short)l;
    }
    ((short8*)wxtH)[fid * 64 + lane] = h8;
    ((short8*)wxtM)[fid * 64 + lane] = m8;
    ((short8*)wxtL)[fid * 64 + lane] = l8;
}

// ---------------------------------------------------------------------------
// Kernel A (MFMA): per block = chunk c x batch b x ALL 512 channels.
// LDS: AF (24 KB, A-fragments) and U (33.4 KB, GEMM output tile) UNIONED --
// AF dies at end of Phase M, U born after -> one 33.4 KB buffer, 4 blocks/CU.
// Phase S: X chunk -> regs -> bf16 h/m/l -> AF.
// Phase M: 6-product emulation (mm,lh,hl,mh,hm,hh smallest-first), 384 MFMA/wave.
// Phase U/scan per m-tile: acc -> U[16][USTRIDE] -> serial scan (2 ch/thread).
// grid (NCHUNK, BATCH) = 4096 blocks, 256 threads.
// ---------------------------------------------------------------------------
__global__ __launch_bounds__(256) void rnn_local_mfma(
    const float* __restrict__ X,          // [L, B, DIN]
    const unsigned short* __restrict__ wxtH,
    const unsigned short* __restrict__ wxtM,
    const unsigned short* __restrict__ wxtL,
    const float* __restrict__ wh,         // [DLAT]
    const float* __restrict__ bh,         // [DLAT]
    float* __restrict__ out,              // [L, B, DLAT] pre-tanh locals
    float* __restrict__ F)                // [NCHUNK, B, DLAT]
{
    // Union: AF needs 24*512*2 = 24576 B; U needs 16*USTRIDE*4 = 33408 B.
    __shared__ __align__(16) char smem[16 * USTRIDE * 4];
    unsigned short* AF = (unsigned short*)smem;
    float* U = (float*)smem;

    const int tid  = threadIdx.x;
    const int c = blockIdx.x, b = blockIdx.y;
    const int w = tid >> 6, lane = tid & 63;

    // ---- Phase S: stage + 3-way convert. 2 frag-slots per thread. ----
#pragma unroll
    for (int sl = 0; sl < 2; ++sl) {
        const int slot = tid + sl * 256;
        const int f  = slot >> 6;        // m*4 + kt  (0..7)
        const int ls = slot & 63;
        const int m  = f >> 2, kt = f & 3;
        const int t  = c * CHUNK + m * 16 + (ls & 15);
        const int kb = kt * 32 + (ls >> 4) * 8;
        const float* p = X + ((size_t)t * BATCH + b) * DIN + kb;
        const float4 va = *(const float4*)p;
        const float4 vb = *(const float4*)(p + 4);
        float v[8] = {va.x, va.y, va.z, va.w, vb.x, vb.y, vb.z, vb.w};
        short8 h8, m8, l8;
#pragma unroll
        for (int i = 0; i < 8; ++i) {
            unsigned short h, mm, l;
            bf16split3(v[i], h, mm, l);
            h8[i] = (short)h; m8[i] = (short)mm; l8[i] = (short)l;
        }
        ((short8*)AF)[(f * 3 + 0) * 64 + ls] = h8;
        ((short8*)AF)[(f * 3 + 1) * 64 + ls] = m8;
        ((short8*)AF)[(f * 3 + 2) * 64 + ls] = l8;
    }
    __syncthreads();

    // ---- Phase M: MFMA. Wave w owns channels [w*128, w*128+128). ----
    f32x4 acc[2][8];
#pragma unroll
    for (int m = 0; m < 2; ++m)
#pragma unroll
        for (int j = 0; j < 8; ++j)
            acc[m][j] = (f32x4){0.f, 0.f, 0.f, 0.f};

    const short8* AFv = (const short8*)AF;
    const short8* BH  = (const short8*)wxtH;
    const short8* BM  = (const short8*)wxtM;
    const short8* BL  = (const short8*)wxtL;

#pragma unroll
    for (int kt = 0; kt < 4; ++kt) {
        const short8 a0h = AFv[((0 * 4 + kt) * 3 + 0) * 64 + lane];
        const short8 a0m = AFv[((0 * 4 + kt) * 3 + 1) * 64 + lane];
        const short8 a0l = AFv[((0 * 4 + kt) * 3 + 2) * 64 + lane];
        const short8 a1h = AFv[((1 * 4 + kt) * 3 + 0) * 64 + lane];
        const short8 a1m = AFv[((1 * 4 + kt) * 3 + 1) * 64 + lane];
        const short8 a1l = AFv[((1 * 4 + kt) * 3 + 2) * 64 + lane];
#pragma unroll
        for (int j = 0; j < 8; ++j) {
            const int idx = (kt * 32 + w * 8 + j) * 64 + lane;
            const short8 bh8 = BH[idx];
            const short8 bm8 = BM[idx];
            const short8 bl8 = BL[idx];
            // smallest-first: mm, al*bh, ah*bl, am*bh, ah*bm, ah*bh
            acc[0][j] = __builtin_amdgcn_mfma_f32_16x16x32_bf16(a0m, bm8, acc[0][j], 0, 0, 0);
            acc[0][j] = __builtin_amdgcn_mfma_f32_16x16x32_bf16(a0l, bh8, acc[0][j], 0, 0, 0);
            acc[0][j] = __builtin_amdgcn_mfma_f32_16x16x32_bf16(a0h, bl8, acc[0][j], 0, 0, 0);
            acc[0][j] = __builtin_amdgcn_mfma_f32_16x16x32_bf16(a0m, bh8, acc[0][j], 0, 0, 0);
            acc[0][j] = __builtin_amdgcn_mfma_f32_16x16x32_bf16(a0h, bm8, acc[0][j], 0, 0, 0);
            acc[0][j] = __builtin_amdgcn_mfma_f32_16x16x32_bf16(a0h, bh8, acc[0][j], 0, 0, 0);
            acc[1][j] = __builtin_amdgcn_mfma_f32_16x16x32_bf16(a1m, bm8, acc[1][j], 0, 0, 0);
            acc[1][j] = __builtin_amdgcn_mfma_f32_16x16x32_bf16(a1l, bh8, acc[1][j], 0, 0, 0);
            acc[1][j] = __builtin_amdgcn_mfma_f32_16x16x32_bf16(a1h, bl8, acc[1][j], 0, 0, 0);
            acc[1][j] = __builtin_amdgcn_mfma_f32_16x16x32_bf16(a1m, bh8, acc[1][j], 0, 0, 0);
            acc[1][j] = __builtin_amdgcn_mfma_f32_16x16x32_bf16(a1h, bm8, acc[1][j], 0, 0, 0);
            acc[1][j] = __builtin_amdgcn_mfma_f32_16x16x32_bf16(a1h, bh8, acc[1][j], 0, 0, 0);
        }
    }

    // ---- Phase U/scan: two m-tiles through the unioned U buffer. ----
    const int ch = tid * 2;                           // 2 channels per thread
    const float2 whv = *(const float2*)(wh + ch);
    const float2 bhv = *(const float2*)(bh + ch);
    float l0 = 0.f, l1 = 0.f;

#pragma unroll
    for (int m = 0; m < 2; ++m) {
        __syncthreads();   // m=0: all AF reads done (union!); m=1: scan0 reads done
        // D layout (m89-verified): col = lane&15, row = (lane>>4)*4 + reg.
#pragma unroll
        for (int j = 0; j < 8; ++j) {
            const int col = w * 128 + j * 16 + (lane & 15);
#pragma unroll
            for (int r4 = 0; r4 < 4; ++r4)
                U[((lane >> 4) * 4 + r4) * USTRIDE + col] = acc[m][j][r4];
        }
        __syncthreads();
        for (int tl = 0; tl < 16; ++tl) {
            const float2 u = *(const float2*)&U[tl * USTRIDE + ch];
            l0 = fmaf(l0, whv.x, u.x + bhv.x);
            l1 = fmaf(l1, whv.y, u.y + bhv.y);
            const int t = c * CHUNK + m * 16 + tl;
            float2 o; o.x = l0; o.y = l1;
            *(float2*)(out + ((size_t)t * BATCH + b) * DLAT + ch) = o;
        }
    }

    float2 fo; fo.x = l0; fo.y = l1;
    *(float2*)(F + ((size_t)c * BATCH + b) * DLAT + ch) = fo;
}

// ---------------------------------------------------------------------------
// Kernel B0: sequential prefix over chunks -> Hpre[c] = state entering chunk c.
// grid (BATCH), block 128 (thread owns float4 of channels). Tiny.
// ---------------------------------------------------------------------------
__global__ __launch_bounds__(128) void rnn_prefix(
    const float* __restrict__ h0,   // [B, DLAT]
    const float* __restrict__ wh,   // [DLAT]
    const float* __restrict__ F,    // [NCHUNK, B, DLAT]
    float* __restrict__ Hpre)       // [NCHUNK, B, DLAT]
{
    const int b  = blockIdx.x;
    const int j4 = threadIdx.x * 4;
    const size_t cb = (size_t)b * DLAT + j4;

    float4 w4 = *(const float4*)(wh + j4);
    float wv[4] = {w4.x, w4.y, w4.z, w4.w};
    float wc[4];
#pragma unroll
    for (int k = 0; k < 4; ++k) {
        float t = wv[k];
        t = t * t; t = t * t; t = t * t; t = t * t; t = t * t;  // wh^32 (>0)
        wc[k] = t;
    }

    float4 h4 = *(const float4*)(h0 + cb);
    float Hv[4] = {h4.x, h4.y, h4.z, h4.w};

    for (int cg = 0; cg < NCHUNK / 4; ++cg) {
        float4 Fv[4];
#pragma unroll
        for (int i = 0; i < 4; ++i)
            Fv[i] = *(const float4*)(F + (size_t)(cg * 4 + i) * (BATCH * DLAT) + cb);
#pragma unroll
        for (int i = 0; i < 4; ++i) {
            float4 o = {Hv[0], Hv[1], Hv[2], Hv[3]};
            *(float4*)(Hpre + (size_t)(cg * 4 + i) * (BATCH * DLAT) + cb) = o;
            Hv[0] = fmaf(Hv[0], wc[0], Fv[i].x);
            Hv[1] = fmaf(Hv[1], wc[1], Fv[i].y);
            Hv[2] = fmaf(Hv[2], wc[2], Fv[i].z);
            Hv[3] = fmaf(Hv[3], wc[3], Fv[i].w);
        }
    }
}

// ---------------------------------------------------------------------------
// Kernel C: pure streaming fixup: out_t = tanh(l_t + wh^{d+1} * Hpre[c]).
// grid (NCHUNK/2, BATCH), block 256 = 2 chunks x 128 threads x float4.
// ---------------------------------------------------------------------------
__global__ __launch_bounds__(256) void rnn_fix2(
    const float* __restrict__ wh,    // [DLAT]
    const float* __restrict__ Hpre,  // [NCHUNK, B, DLAT]
    float* __restrict__ out)         // [L, B, DLAT] in-place
{
    const int tid = threadIdx.x;
    const int c   = blockIdx.x * 2 + (tid >> 7);
    const int b   = blockIdx.y;
    const int j4  = (tid & 127) * 4;
    const size_t cb = (size_t)b * DLAT + j4;

    float4 w4 = *(const float4*)(wh + j4);
    float4 H4 = *(const float4*)(Hpre + (size_t)c * (BATCH * DLAT) + cb);
    float wv[4] = {w4.x, w4.y, w4.z, w4.w};
    float Hv[4] = {H4.x, H4.y, H4.z, H4.w};

    float sc[4] = {wv[0], wv[1], wv[2], wv[3]};
#pragma unroll 4
    for (int d = 0; d < CHUNK; ++d) {
        const size_t off = ((size_t)(c * CHUNK + d) * BATCH + b) * DLAT + j4;
        float4 l4 = *(const float4*)(out + off);
        float4 res;
        res.x = tanhf(fmaf(sc[0], Hv[0], l4.x));
        res.y = tanhf(fmaf(sc[1], Hv[1], l4.y));
        res.z = tanhf(fmaf(sc[2], Hv[2], l4.z));
        res.w = tanhf(fmaf(sc[3], Hv[3], l4.w));
        *(float4*)(out + off) = res;
        sc[0] *= wv[0]; sc[1] *= wv[1]; sc[2] *= wv[2]; sc[3] *= wv[3];
    }
}

// Fallback fixup (ws too small for Hpre): fold H per block from F.
__global__ __launch_bounds__(256) void rnn_fix(
    const float* __restrict__ h0, const float* __restrict__ wh,
    const float* __restrict__ F, float* __restrict__ out)
{
    const int tid = threadIdx.x;
    const int c   = blockIdx.x * 2 + (tid >> 7);
    const int b   = blockIdx.y;
    const int j4  = (tid & 127) * 4;
    const size_t cb = (size_t)b * DLAT + j4;

    float4 h4 = *(const float4*)(h0 + cb);
    float4 w4 = *(const float4*)(wh + j4);
    float Hv[4] = {h4.x, h4.y, h4.z, h4.w};
    float wv[4] = {w4.x, w4.y, w4.z, w4.w};
    float wc[4];
#pragma unroll
    for (int k = 0; k < 4; ++k) {
        float t = wv[k];
        t = t * t; t = t * t; t = t * t; t = t * t; t = t * t;
        wc[k] = t;
    }
    for (int cc = 0; cc < c; ++cc) {
        const float4 Fv = *(const float4*)(F + ((size_t)cc * BATCH + b) * DLAT + j4);
        Hv[0] = fmaf(Hv[0], wc[0], Fv.x);
        Hv[1] = fmaf(Hv[1], wc[1], Fv.y);
        Hv[2] = fmaf(Hv[2], wc[2], Fv.z);
        Hv[3] = fmaf(Hv[3], wc[3], Fv.w);
    }
    float sc[4] = {wv[0], wv[1], wv[2], wv[3]};
    for (int d = 0; d < CHUNK; ++d) {
        const size_t off = ((size_t)(c * CHUNK + d) * BATCH + b) * DLAT + j4;
        float4 l4 = *(const float4*)(out + off);
        float4 res;
        res.x = tanhf(fmaf(sc[0], Hv[0], l4.x));
        res.y = tanhf(fmaf(sc[1], Hv[1], l4.y));
        res.z = tanhf(fmaf(sc[2], Hv[2], l4.z));
        res.w = tanhf(fmaf(sc[3], Hv[3], l4.w));
        *(float4*)(out + off) = res;
        sc[0] *= wv[0]; sc[1] *= wv[1]; sc[2] *= wv[2]; sc[3] *= wv[3];
    }
}

extern "C" void kernel_launch(void* const* d_in, const int* in_sizes, int n_in,
                              void* d_out, int out_size, void* d_ws, size_t ws_size,
                              hipStream_t stream) {
    const float* X  = (const float*)d_in[0];
    const float* h0 = (const float*)d_in[1];
    const float* wx = (const float*)d_in[2];
    const float* wh = (const float*)d_in[3];
    const float* bh = (const float*)d_in[4];
    float* out = (float*)d_out;

    const size_t seg = (size_t)NCHUNK * BATCH * DLAT;   // 2M floats = 8 MiB
    const size_t wxt_elems = 4 * 32 * 64 * 8;           // 65536 ushorts = 128 KB
    float* F = (float*)d_ws;
    unsigned short* wxtH = (unsigned short*)(F + seg);
    unsigned short* wxtM = wxtH + wxt_elems;
    unsigned short* wxtL = wxtM + wxt_elems;
    float* Hpre = (float*)(wxtL + wxt_elems);

    const size_t need_mid  = seg * 4 + wxt_elems * 3 * 2;   // F + wxt  = 8.375 MiB
    const size_t need_full = need_mid + seg * 4;            // + Hpre   = 16.375 MiB

    wx_transform<<<dim3(32), dim3(256), 0, stream>>>(wx, wxtH, wxtM, wxtL);
    rnn_local_mfma<<<dim3(NCHUNK, BATCH), dim3(256), 0, stream>>>(
        X, wxtH, wxtM, wxtL, wh, bh, out, F);
    if (ws_size >= need_full) {
        rnn_prefix<<<dim3(BATCH), dim3(128), 0, stream>>>(h0, wh, F, Hpre);
        rnn_fix2<<<dim3(NCHUNK / 2, BATCH), dim3(256), 0, stream>>>(wh, Hpre, out);
    } else {
        rnn_fix<<<dim3(NCHUNK / 2, BATCH), dim3(256), 0, stream>>>(h0, wh, F, out);
    }
}